// Round 9
// baseline (30.575 us; speedup 1.0000x reference)
//
#include <hip/hip_runtime.h>

// Problem constants (match reference)
constexpr int B = 128, N = 900, C = 91, M = 100;
constexpr float ALPHA = 0.25f;
constexpr float W_CLASS = 2.0f;
constexpr float W_BBOX = 5.0f;
constexpr float W_GIOU = 2.0f;

constexpr int NBX  = 15;          // blocks in n per batch
constexpr int ROWS = N / NBX;     // 60 rows per block
constexpr int BLK  = 256;
constexpr int MQ   = M / 4;       // 25 output quads per row
constexpr int NGRP = 10;          // row-groups; 250 active threads in phase C
constexpr int KIT  = ROWS / NGRP; // 6 consecutive rows per thread

constexpr int NLOG  = ROWS * C;   // 5460 floats of logits per block
constexpr int NLOG4 = NLOG / 4;   // 1365 float4 quads (exact)
constexpr int SIT   = (NLOG4 + BLK - 1) / BLK;  // 6 DMA iterations

// Async global->LDS DMA, 16B per active lane. LDS dest = wave-uniform base
// + lane*16 (m104 semantics); global src is per-lane.
__device__ __forceinline__ void gload_lds16(const void* g, void* l) {
    __builtin_amdgcn_global_load_lds(
        (const __attribute__((address_space(1))) void*)g,
        (__attribute__((address_space(3))) void*)l,
        16, 0, 0);
}

__global__ __launch_bounds__(BLK) void hungarian_cost_kernel(
    const float* __restrict__ logits,   // [B, N, C]
    const float* __restrict__ pboxes,   // [B, N, 4] cxcywh
    const int*   __restrict__ tlabels,  // [B, M]
    const float* __restrict__ tboxes,   // [B, M, 4] cxcywh
    float* __restrict__ out)            // [B, N, M]
{
    __shared__ float  slog[NLOG];       // 21840 B raw logits (linear)
    __shared__ float4 spb[ROWS];        // 960 B pred boxes

    const int b   = blockIdx.y;
    const int n0  = blockIdx.x * ROWS;
    const int tid = threadIdx.x;

    // ---- DMA staging: zero VGPR round-trip, deep queue ----
    const float4* lsrc4 = reinterpret_cast<const float4*>(
        logits + ((size_t)b * N + n0) * C);                  // 16B aligned
    const float4* pbp = reinterpret_cast<const float4*>(pboxes) + (size_t)b * N + n0;

    if (tid < ROWS)   // lanes 0..59 of wave 0; lptr uniform, HW adds lane*16
        gload_lds16(pbp + tid, spb);

    #pragma unroll
    for (int i = 0; i < SIT; ++i) {
        const int q = i * BLK + tid;                 // quad index
        if (q < NLOG4) {
            float4* ldst = reinterpret_cast<float4*>(slog) + (q & ~63); // wave base
            gload_lds16(lsrc4 + q, ldst);
        }
    }

    // ---- Targets -> registers (overlaps DMA; drained by barrier) ----
    const int  mq     = tid % MQ;       // 0..24
    const int  rgrp   = tid / MQ;       // 0..10
    const bool active = (rgrp < NGRP);

    float tx0[4], ty0[4], tx1[4], ty1[4], tar[4];
    int   labj[4] = {0, 0, 0, 0};
    if (active) {
        const int4 l4 = reinterpret_cast<const int4*>(tlabels + (size_t)b * M)[mq];
        labj[0] = l4.x; labj[1] = l4.y; labj[2] = l4.z; labj[3] = l4.w;
        const float4* tbp = reinterpret_cast<const float4*>(tboxes) + (size_t)b * M;
        #pragma unroll
        for (int j = 0; j < 4; ++j) {
            const float4 t = tbp[mq * 4 + j];
            tx0[j] = t.x - 0.5f * t.z;  ty0[j] = t.y - 0.5f * t.w;
            tx1[j] = t.x + 0.5f * t.z;  ty1[j] = t.y + 0.5f * t.w;
            tar[j] = (tx1[j] - tx0[j]) * (ty1[j] - ty0[j]);
        }
    }

    __syncthreads();    // drains vmcnt (DMA) + syncs LDS
    if (!active) return;

    const int r0 = rgrp * KIT;          // 6 consecutive rows per thread
    float4* outt = reinterpret_cast<float4*>(out)
                 + ((size_t)(b * N + n0 + r0)) * MQ + mq;

    // ---- Hot loop: pure LDS + VALU; TLP (7 waves/SIMD) hides latency ----
    #pragma unroll 1
    for (int k = 0; k < KIT; ++k) {
        const int row = r0 + k;
        const float4 p = spb[row];      // broadcast ds_read_b128 (3 addrs/wave)

        float xg[4];
        #pragma unroll
        for (int j = 0; j < 4; ++j)
            xg[j] = slog[row * C + labj[j]];    // ds_read_b32, imm k*364

        const float px0 = p.x - 0.5f * p.z, py0 = p.y - 0.5f * p.w;
        const float px1 = p.x + 0.5f * p.z, py1 = p.y + 0.5f * p.w;
        const float parea = (px1 - px0) * (py1 - py0);

        float4 res;
        float* rp = &res.x;
        #pragma unroll
        for (int j = 0; j < 4; ++j) {
            // focal: s = 1/(1+e), e = exp(-x); -log(s)=log(1+e); -log(1-s)=x+log(1+e)
            const float x    = xg[j];
            const float e    = __expf(-x);
            const float onep = 1.0f + e;
            const float s    = __builtin_amdgcn_rcpf(onep);
            const float om   = e * s;            // 1 - s
            const float L    = __logf(onep);     // = -log(s)
            const float ccls = W_CLASS * (ALPHA * om * om * L
                                        - (1.0f - ALPHA) * s * s * (x + L));

            // L1 via xyxy deltas: |pc-tc| = 0.5|dx0+dx1|, |pw-tw| = |dx1-dx0|
            const float dx0 = px0 - tx0[j], dx1 = px1 - tx1[j];
            const float dy0 = py0 - ty0[j], dy1 = py1 - ty1[j];
            const float l1 = 0.5f * (fabsf(dx0 + dx1) + fabsf(dy0 + dy1))
                           + fabsf(dx1 - dx0) + fabsf(dy1 - dy0);

            // GIoU, single reciprocal:
            // giou = (inter*earea - uni*(earea-uni)) / (uni*earea)
            const float iw = fmaxf(fminf(px1, tx1[j]) - fmaxf(px0, tx0[j]), 0.0f);
            const float ih = fmaxf(fminf(py1, ty1[j]) - fmaxf(py0, ty0[j]), 0.0f);
            const float inter = iw * ih;
            const float uni   = parea + tar[j] - inter;

            const float ew = fmaxf(px1, tx1[j]) - fminf(px0, tx0[j]);
            const float eh = fmaxf(py1, ty1[j]) - fminf(py0, ty0[j]);
            const float earea = ew * eh;

            const float num  = inter * earea - uni * (earea - uni);
            const float rcpD = __builtin_amdgcn_rcpf(uni * earea);

            rp[j] = ccls + W_BBOX * l1 - W_GIOU * (num * rcpD);
        }

        outt[(size_t)k * MQ] = res;     // byte stride 400: imm offset
    }
}

extern "C" void kernel_launch(void* const* d_in, const int* in_sizes, int n_in,
                              void* d_out, int out_size, void* d_ws, size_t ws_size,
                              hipStream_t stream) {
    const float* logits  = (const float*)d_in[0];
    const float* pboxes  = (const float*)d_in[1];
    const int*   tlabels = (const int*)d_in[2];
    const float* tboxes  = (const float*)d_in[3];
    float* out = (float*)d_out;

    dim3 grid(NBX, B);
    dim3 block(BLK);
    hipLaunchKernelGGL(hungarian_cost_kernel, grid, block, 0, stream,
                       logits, pboxes, tlabels, tboxes, out);
}

// Round 10
// 27.295 us; speedup vs baseline: 1.1202x; 1.1202x over previous
//
#include <hip/hip_runtime.h>

// Problem constants (match reference)
constexpr int B = 128, N = 900, C = 91, M = 100;
constexpr float ALPHA = 0.25f;
constexpr float W_CLASS = 2.0f;
constexpr float W_BBOX = 5.0f;
constexpr float W_GIOU = 2.0f;

constexpr int NBX  = 15;          // blocks in n per batch
constexpr int ROWS = N / NBX;     // 60 rows per block
constexpr int BLK  = 256;
constexpr int MQ   = M / 4;       // 25 output quads per row
constexpr int NGRP = 10;          // row-groups; 250 active threads
constexpr int KIT  = ROWS / NGRP; // 6 iterations per thread (exact)

typedef float f32x4 __attribute__((ext_vector_type(4)));

__global__ __launch_bounds__(BLK) void hungarian_cost_kernel(
    const float* __restrict__ logits,   // [B, N, C]
    const float* __restrict__ pboxes,   // [B, N, 4] cxcywh
    const int*   __restrict__ tlabels,  // [B, M]
    const float* __restrict__ tboxes,   // [B, M, 4] cxcywh
    float* __restrict__ out)            // [B, N, M]
{
    const int b   = blockIdx.y;
    const int n0  = blockIdx.x * ROWS;
    const int tid = threadIdx.x;

    const int mq   = tid % MQ;        // 0..24 (quad of m)
    const int rgrp = tid / MQ;        // 0..10
    if (rgrp >= NGRP) return;         // 6 idle threads; no barriers anywhere

    const float*  lbase = logits + ((size_t)b * N + n0) * C;
    const float4* pbp   = reinterpret_cast<const float4*>(pboxes) + (size_t)b * N + n0;
    f32x4*        outq  = reinterpret_cast<f32x4*>(out) + ((size_t)b * N + n0) * MQ;

    // ---- Load labels first (gather addresses depend on them) ----
    const int4 l4 = reinterpret_cast<const int4*>(tlabels + (size_t)b * M)[mq];
    int labj[4] = {l4.x, l4.y, l4.z, l4.w};

    // ---- Issue ALL hot-loop loads up front: 6 pred-box + 24 logit gathers ----
    float4 pv[KIT];
    float  xsv[KIT][4];
    #pragma unroll
    for (int k = 0; k < KIT; ++k) {
        const int row = rgrp + NGRP * k;
        pv[k] = pbp[row];
        const float* lr = lbase + row * C;
        #pragma unroll
        for (int j = 0; j < 4; ++j) xsv[k][j] = lr[labj[j]];
    }

    // ---- Targets -> registers (loaded once, reused 6x) ----
    float tcx[4], tcy[4], twd[4], tht[4];
    float tx0[4], ty0[4], tx1[4], ty1[4], tar[4];
    {
        const float4* tbp = reinterpret_cast<const float4*>(tboxes) + (size_t)b * M;
        #pragma unroll
        for (int j = 0; j < 4; ++j) {
            const float4 t = tbp[mq * 4 + j];
            tcx[j] = t.x; tcy[j] = t.y; twd[j] = t.z; tht[j] = t.w;
            tx0[j] = t.x - 0.5f * t.z;  ty0[j] = t.y - 0.5f * t.w;
            tx1[j] = t.x + 0.5f * t.z;  ty1[j] = t.y + 0.5f * t.w;
            tar[j] = (tx1[j] - tx0[j]) * (ty1[j] - ty0[j]);
        }
    }

    // ---- Compute all 6 iterations against in-flight loads ----
    #pragma unroll
    for (int k = 0; k < KIT; ++k) {
        const int row = rgrp + NGRP * k;
        const float4 p = pv[k];

        const float px0 = p.x - 0.5f * p.z, py0 = p.y - 0.5f * p.w;
        const float px1 = p.x + 0.5f * p.z, py1 = p.y + 0.5f * p.w;
        const float parea = (px1 - px0) * (py1 - py0);

        f32x4 res;
        #pragma unroll
        for (int j = 0; j < 4; ++j) {
            // focal class cost:  s = 1/(1+e), e = exp(-x)
            // -log(s) = log(1+e);  -log(1-s) = x + log(1+e)
            const float x    = xsv[k][j];
            const float e    = __expf(-x);
            const float onep = 1.0f + e;
            const float s    = __builtin_amdgcn_rcpf(onep);
            const float om   = e * s;            // 1 - s
            const float L    = __logf(onep);     // = -log(s)
            const float ccls = W_CLASS * (ALPHA * om * om * L
                                        - (1.0f - ALPHA) * s * s * (x + L));

            // L1 cdist on cxcywh (direct form: 4 sub + 3 abs-mod adds)
            const float l1 = fabsf(p.x - tcx[j]) + fabsf(p.y - tcy[j]) +
                             fabsf(p.z - twd[j]) + fabsf(p.w - tht[j]);

            // GIoU on xyxy, single reciprocal:
            // giou = (inter*earea - uni*(earea-uni)) / (uni*earea)
            const float iw = fmaxf(fminf(px1, tx1[j]) - fmaxf(px0, tx0[j]), 0.0f);
            const float ih = fmaxf(fminf(py1, ty1[j]) - fmaxf(py0, ty0[j]), 0.0f);
            const float inter = iw * ih;
            const float uni   = parea + tar[j] - inter;

            const float ew = fmaxf(px1, tx1[j]) - fminf(px0, tx0[j]);
            const float eh = fmaxf(py1, ty1[j]) - fminf(py0, ty0[j]);
            const float earea = ew * eh;

            const float num  = inter * earea - uni * (earea - uni);
            const float rcpD = __builtin_amdgcn_rcpf(uni * earea);

            res[j] = ccls + W_BBOX * l1 - W_GIOU * (num * rcpD);
        }

        // Non-temporal store: no L2/L3 write-allocate (RFO) fetch of out lines
        __builtin_nontemporal_store(res, &outq[(size_t)row * MQ + mq]);
    }
}

extern "C" void kernel_launch(void* const* d_in, const int* in_sizes, int n_in,
                              void* d_out, int out_size, void* d_ws, size_t ws_size,
                              hipStream_t stream) {
    const float* logits  = (const float*)d_in[0];
    const float* pboxes  = (const float*)d_in[1];
    const int*   tlabels = (const int*)d_in[2];
    const float* tboxes  = (const float*)d_in[3];
    float* out = (float*)d_out;

    dim3 grid(NBX, B);
    dim3 block(BLK);
    hipLaunchKernelGGL(hungarian_cost_kernel, grid, block, 0, stream,
                       logits, pboxes, tlabels, tboxes, out);
}

// Round 11
// 26.940 us; speedup vs baseline: 1.1349x; 1.0132x over previous
//
#include <hip/hip_runtime.h>

// Problem constants (match reference)
constexpr int B = 128, N = 900, C = 91, M = 100;
// ALPHA=0.25, W_CLASS=2 folded analytically into focal form below:
// ccls = W_CLASS*(ALPHA*(1-s)^2*L - (1-ALPHA)*s^2*(x+L))
//      = L*(0.5 - s - s^2) - 1.5*s^2*x          (with L = log(1+exp(-x)))
constexpr float W_BBOX = 5.0f;
constexpr float W_GIOU = 2.0f;

constexpr int NBX  = 15;          // blocks in n per batch
constexpr int ROWS = N / NBX;     // 60 rows per block
constexpr int BLK  = 256;
constexpr int MQ   = M / 4;       // 25 output quads per row
constexpr int NGRP = 10;          // row-groups; 250 active threads
constexpr int KIT  = ROWS / NGRP; // 6 iterations per thread (exact)

typedef float f32x4 __attribute__((ext_vector_type(4)));

__global__ __launch_bounds__(BLK) void hungarian_cost_kernel(
    const float* __restrict__ logits,   // [B, N, C]
    const float* __restrict__ pboxes,   // [B, N, 4] cxcywh
    const int*   __restrict__ tlabels,  // [B, M]
    const float* __restrict__ tboxes,   // [B, M, 4] cxcywh
    float* __restrict__ out)            // [B, N, M]
{
    const int b   = blockIdx.y;
    const int n0  = blockIdx.x * ROWS;
    const int tid = threadIdx.x;

    const int mq   = tid % MQ;        // 0..24 (quad of m)
    const int rgrp = tid / MQ;        // 0..10
    if (rgrp >= NGRP) return;         // 6 idle threads; no barriers anywhere

    const float*  lbase = logits + ((size_t)b * N + n0) * C;
    const float4* pbp   = reinterpret_cast<const float4*>(pboxes) + (size_t)b * N + n0;
    f32x4*        outq  = reinterpret_cast<f32x4*>(out) + ((size_t)b * N + n0) * MQ;

    // ---- Labels (gather addresses depend on them) ----
    const int4 l4 = reinterpret_cast<const int4*>(tlabels + (size_t)b * M)[mq];
    const int labj[4] = {l4.x, l4.y, l4.z, l4.w};

    // ---- Targets -> registers: xyxy + area only (20 VGPR) ----
    float tx0[4], ty0[4], tx1[4], ty1[4], tar[4];
    {
        const float4* tbp = reinterpret_cast<const float4*>(tboxes) + (size_t)b * M;
        #pragma unroll
        for (int j = 0; j < 4; ++j) {
            const float4 t = tbp[mq * 4 + j];
            tx0[j] = t.x - 0.5f * t.z;  ty0[j] = t.y - 0.5f * t.w;
            tx1[j] = t.x + 0.5f * t.z;  ty1[j] = t.y + 0.5f * t.w;
            tar[j] = (tx1[j] - tx0[j]) * (ty1[j] - ty0[j]);
        }
    }

    // ---- Depth-2 software pipeline: prologue loads for k=0 ----
    float4 pA, pB;
    float  xA[4], xB[4];
    {
        const int row0 = rgrp;                   // ROWOF(0)
        pA = pbp[row0];
        const float* lr = lbase + row0 * C;
        #pragma unroll
        for (int j = 0; j < 4; ++j) xA[j] = lr[labj[j]];
    }

    #pragma unroll
    for (int k = 0; k < KIT; ++k) {
        const int row = rgrp + NGRP * k;

        // ---- Issue k+1's loads BEFORE computing k; fence so they stay ----
        if (k + 1 < KIT) {
            const int rown = row + NGRP;
            pB = pbp[rown];
            const float* lr = lbase + rown * C;
            #pragma unroll
            for (int j = 0; j < 4; ++j) xB[j] = lr[labj[j]];
        }
        __builtin_amdgcn_sched_barrier(0);   // loads above, compute below

        const float4 p = pA;
        const float px0 = p.x - 0.5f * p.z, py0 = p.y - 0.5f * p.w;
        const float px1 = p.x + 0.5f * p.z, py1 = p.y + 0.5f * p.w;
        const float parea = (px1 - px0) * (py1 - py0);

        f32x4 res;
        #pragma unroll
        for (int j = 0; j < 4; ++j) {
            // focal class cost (ALPHA/W_CLASS folded):
            // e = exp(-x); L = log(1+e); s = 1/(1+e)
            // ccls = L*(0.5 - s - s^2) - 1.5*s^2*x
            const float x    = xA[j];
            const float e    = __expf(-x);
            const float onep = 1.0f + e;
            const float s    = __builtin_amdgcn_rcpf(onep);
            const float L    = __logf(onep);
            const float s2   = s * s;
            const float coef = (0.5f - s) - s2;
            const float ccls = L * coef - 1.5f * s2 * x;

            // L1 via xyxy deltas: |pc-tc| = 0.5|dx0+dx1|, |pw-tw| = |dx1-dx0|
            const float dx0 = px0 - tx0[j], dx1 = px1 - tx1[j];
            const float dy0 = py0 - ty0[j], dy1 = py1 - ty1[j];
            const float l1 = 0.5f * (fabsf(dx0 + dx1) + fabsf(dy0 + dy1))
                           + fabsf(dx1 - dx0) + fabsf(dy1 - dy0);

            // GIoU, single reciprocal:
            // giou = (inter*earea - uni*(earea-uni)) / (uni*earea)
            const float iw = fmaxf(fminf(px1, tx1[j]) - fmaxf(px0, tx0[j]), 0.0f);
            const float ih = fmaxf(fminf(py1, ty1[j]) - fmaxf(py0, ty0[j]), 0.0f);
            const float inter = iw * ih;
            const float uni   = parea + tar[j] - inter;

            const float ew = fmaxf(px1, tx1[j]) - fminf(px0, tx0[j]);
            const float eh = fmaxf(py1, ty1[j]) - fminf(py0, ty0[j]);
            const float earea = ew * eh;

            const float num  = inter * earea - uni * (earea - uni);
            const float rcpD = __builtin_amdgcn_rcpf(uni * earea);

            res[j] = ccls + W_BBOX * l1 - W_GIOU * (num * rcpD);
        }

        // Non-temporal store: no write-allocate RFO on out lines
        __builtin_nontemporal_store(res, &outq[(size_t)row * MQ + mq]);

        // rotate pipeline regs (renames under full unroll)
        pA = pB;
        #pragma unroll
        for (int j = 0; j < 4; ++j) xA[j] = xB[j];
    }
}

extern "C" void kernel_launch(void* const* d_in, const int* in_sizes, int n_in,
                              void* d_out, int out_size, void* d_ws, size_t ws_size,
                              hipStream_t stream) {
    const float* logits  = (const float*)d_in[0];
    const float* pboxes  = (const float*)d_in[1];
    const int*   tlabels = (const int*)d_in[2];
    const float* tboxes  = (const float*)d_in[3];
    float* out = (float*)d_out;

    dim3 grid(NBX, B);
    dim3 block(BLK);
    hipLaunchKernelGGL(hungarian_cost_kernel, grid, block, 0, stream,
                       logits, pboxes, tlabels, tboxes, out);
}